// Round 4
// baseline (436.142 us; speedup 1.0000x reference)
//
#include <hip/hip_runtime.h>
#include <math.h>

#define N_NODES 100000
#define N_EDGES 1600000
#define IN_DIM  256
#define HIDDEN  64

// ---- mono geometry: 512 blocks x 1024 thr = exactly 2 blocks/CU ------------
#define NB      512
// phase 1 deg: 128 blocks = 32 chunks x 4 ranges (byte-packed, LDS 25.6 KB)
#define DEGB    128
#define D_CH    32
#define D_QPB   12500      // int4 groups per chunk (50000 edges)
#define D_PR    4
#define D_DNR   25600
#define D_DW    6400
// phase 1 s-stream: 384 blocks
#define SBLK    384
// phase 3 scatter: 512 blocks = 64 chunks x 8 ranges (LDS 50,176 B)
#define S_CH    64
#define S_QPB   6250       // int4 groups per chunk (25000 edges)
#define S_SR    8
#define S_RANGE 12544

// ---------------------------------------------------------------------------
// Software grid barrier for a co-resident grid (512 blocks guaranteed by
// __launch_bounds__(1024,8) reg cap + 50KB LDS). Monotonic flag, agent scope.
// __syncthreads drains each wave's stores (compiler emits vmcnt(0) before
// s_barrier); thread0's __threadfence writes back XCD L2 (cross-XCD vis).
// ---------------------------------------------------------------------------
__device__ __forceinline__ void grid_barrier(int* cnt, int* flag, int target) {
    __syncthreads();
    if (threadIdx.x == 0) {
        __threadfence();
        if (__hip_atomic_fetch_add(cnt, 1, __ATOMIC_ACQ_REL, __HIP_MEMORY_SCOPE_AGENT)
            == NB - 1) {
            __hip_atomic_store(cnt, 0, __ATOMIC_RELAXED, __HIP_MEMORY_SCOPE_AGENT);
            __hip_atomic_fetch_add(flag, 1, __ATOMIC_RELEASE, __HIP_MEMORY_SCOPE_AGENT);
        } else {
            while (__hip_atomic_load(flag, __ATOMIC_ACQUIRE, __HIP_MEMORY_SCOPE_AGENT)
                   < target) {
                __builtin_amdgcn_s_sleep(2);
            }
        }
    }
    __syncthreads();
}

// ---------------------------------------------------------------------------
// mono: all four phases in one persistent kernel (validated R1 per-phase code).
// ---------------------------------------------------------------------------
__global__ void __launch_bounds__(1024, 8) mono_kernel(
    const float* __restrict__ x, const float* __restrict__ W,
    const float* __restrict__ w2, const float* __restrict__ b,
    const float* __restrict__ b2,
    const int4* __restrict__ src4, const int4* __restrict__ dst4,
    unsigned* __restrict__ partialD, float* __restrict__ partialU,
    float* __restrict__ s, float* __restrict__ t, float* __restrict__ dinv,
    int* __restrict__ bar, float* __restrict__ out)
{
    __shared__ __align__(16) float smem[S_RANGE];    // 50,176 B, reused per phase
    const int bid = blockIdx.x, tid = threadIdx.x;

    // ---------------- phase 1: deg-hist (128 blk) || s-stream (384 blk) -----
    if (bid < DEGB) {
        unsigned* hist = (unsigned*)smem;
        const int r  = bid & (D_PR - 1);
        const int bb = bid >> 2;
        const int nbase = r * D_DNR;
        for (int i = tid; i < D_DW; i += 1024) hist[i] = 0u;
        __syncthreads();
        const int q0 = bb * D_QPB;
        for (int k = tid; k < D_QPB; k += 1024) {
            int4 d4 = dst4[q0 + k];
            int d0 = d4.x - nbase, d1 = d4.y - nbase, d2 = d4.z - nbase, d3 = d4.w - nbase;
            if ((unsigned)d0 < (unsigned)D_DNR) atomicAdd(&hist[d0 >> 2], 1u << ((d0 & 3) * 8));
            if ((unsigned)d1 < (unsigned)D_DNR) atomicAdd(&hist[d1 >> 2], 1u << ((d1 & 3) * 8));
            if ((unsigned)d2 < (unsigned)D_DNR) atomicAdd(&hist[d2 >> 2], 1u << ((d2 & 3) * 8));
            if ((unsigned)d3 < (unsigned)D_DNR) atomicAdd(&hist[d3 >> 2], 1u << ((d3 & 3) * 8));
        }
        __syncthreads();
        unsigned* outp = partialD + (size_t)bid * D_DW;
        for (int i = tid; i < D_DW; i += 1024) outp[i] = hist[i];
    } else {
        float* vsh = smem;
        if (tid < IN_DIM) {
            const float4* wr  = (const float4*)(W + tid * HIDDEN);
            const float4* w2r = (const float4*)w2;
            float acc = 0.f;
            #pragma unroll
            for (int j = 0; j < HIDDEN / 4; ++j) {
                float4 a = wr[j], q = w2r[j];
                acc += a.x * q.x + a.y * q.y + a.z * q.z + a.w * q.w;
            }
            vsh[tid] = acc;
        }
        __syncthreads();
        const int wid  = tid >> 6;
        const int lane = tid & 63;
        const int g    = lane >> 4;
        const int l16  = lane & 15;
        const float4* vr = (const float4*)vsh;
        float4 vv0 = vr[l16];
        float4 vv1 = vr[l16 + 16];
        float4 vv2 = vr[l16 + 32];
        float4 vv3 = vr[l16 + 48];
        #pragma unroll 2
        for (int n0 = ((bid - DEGB) * 16 + wid) * 4; n0 < N_NODES; n0 += SBLK * 16 * 4) {
            const float4* xr = (const float4*)(x + (size_t)(n0 + g) * IN_DIM);
            float4 a0 = xr[l16];
            float4 a1 = xr[l16 + 16];
            float4 a2 = xr[l16 + 32];
            float4 a3 = xr[l16 + 48];
            float d = a0.x * vv0.x + a0.y * vv0.y + a0.z * vv0.z + a0.w * vv0.w
                    + a1.x * vv1.x + a1.y * vv1.y + a1.z * vv1.z + a1.w * vv1.w
                    + a2.x * vv2.x + a2.y * vv2.y + a2.z * vv2.z + a2.w * vv2.w
                    + a3.x * vv3.x + a3.y * vv3.y + a3.z * vv3.z + a3.w * vv3.w;
            d += __shfl_down(d, 8, 16);
            d += __shfl_down(d, 4, 16);
            d += __shfl_down(d, 2, 16);
            d += __shfl_down(d, 1, 16);
            if (l16 == 0) s[n0 + g] = d;
        }
    }
    grid_barrier(bar, bar + 1, 1);

    // ---------------- phase 2: merge deg partials -> dinv, t ----------------
    {
        const int w = bid * 1024 + tid;
        if (w < N_NODES / 4) {                 // 25000 words (blocks 0..24)
            const int r = w / D_DW, j = w - r * D_DW;
            unsigned a0 = 0, a1 = 0, a2 = 0, a3 = 0;
            #pragma unroll 8
            for (int bb = 0; bb < D_CH; ++bb) {
                unsigned p = partialD[(size_t)(bb * D_PR + r) * D_DW + j];
                a0 += p & 255u; a1 += (p >> 8) & 255u;
                a2 += (p >> 16) & 255u; a3 += p >> 24;
            }
            const int n0 = w * 4;
            float4 sv = *(const float4*)(s + n0);
            float4 di, tv;
            di.x = rsqrtf((float)(a0 + 1)); di.y = rsqrtf((float)(a1 + 1));
            di.z = rsqrtf((float)(a2 + 1)); di.w = rsqrtf((float)(a3 + 1));
            tv.x = di.x * sv.x; tv.y = di.y * sv.y;
            tv.z = di.z * sv.z; tv.w = di.w * sv.w;
            *(float4*)(dinv + n0) = di;
            *(float4*)(t + n0) = tv;
        }
    }
    grid_barrier(bar, bar + 1, 2);

    // ---------------- phase 3: u-scatter via LDS hist -----------------------
    {
        float* acc = smem;
        const int r  = bid & (S_SR - 1);
        const int bb = bid >> 3;
        const int nbase = r * S_RANGE;
        for (int i = tid; i < S_RANGE; i += 1024) acc[i] = 0.f;
        __syncthreads();
        const int q0 = bb * S_QPB;
        for (int k = tid; k < S_QPB; k += 1024) {
            int4 d4 = dst4[q0 + k];
            int4 s4 = src4[q0 + k];
            int d0 = d4.x - nbase, d1 = d4.y - nbase, d2 = d4.z - nbase, d3 = d4.w - nbase;
            if ((unsigned)d0 < (unsigned)S_RANGE) atomicAdd(&acc[d0], t[s4.x]);
            if ((unsigned)d1 < (unsigned)S_RANGE) atomicAdd(&acc[d1], t[s4.y]);
            if ((unsigned)d2 < (unsigned)S_RANGE) atomicAdd(&acc[d2], t[s4.z]);
            if ((unsigned)d3 < (unsigned)S_RANGE) atomicAdd(&acc[d3], t[s4.w]);
        }
        __syncthreads();
        float* outp = partialU + (size_t)bid * S_RANGE;
        for (int i = tid; i < S_RANGE; i += 1024) outp[i] = acc[i];
    }
    grid_barrier(bar, bar + 1, 3);

    // ---------------- phase 4: merge u partials + sigmoid -------------------
    {
        float c = b2[0];
        #pragma unroll 8
        for (int j = 0; j < HIDDEN; ++j) c += b[j] * w2[j];
        const int gid = bid * 1024 + tid;
        const int w = gid >> 3, p = gid & 7;     // 8 lanes per word
        if (w < 25088) {
            const int n0 = w * 4;
            const int r = n0 / S_RANGE, j = n0 - r * S_RANGE;
            float4 u = make_float4(0.f, 0.f, 0.f, 0.f);
            #pragma unroll
            for (int q = 0; q < 8; ++q) {
                float4 pp = *(const float4*)(partialU
                              + (size_t)((p + 8 * q) * S_SR + r) * S_RANGE + j);
                u.x += pp.x; u.y += pp.y; u.z += pp.z; u.w += pp.w;
            }
            #pragma unroll
            for (int off = 4; off > 0; off >>= 1) {
                u.x += __shfl_down(u.x, off, 8);
                u.y += __shfl_down(u.y, off, 8);
                u.z += __shfl_down(u.z, off, 8);
                u.w += __shfl_down(u.w, off, 8);
            }
            if (p == 0) {
                float4 di = *(const float4*)(dinv + n0);
                float4 sv = *(const float4*)(s + n0);
                float4 o;
                o.x = 1.f / (1.f + expf(-(di.x * (u.x + di.x * sv.x) + c)));
                o.y = 1.f / (1.f + expf(-(di.y * (u.y + di.y * sv.y) + c)));
                o.z = 1.f / (1.f + expf(-(di.z * (u.z + di.z * sv.z) + c)));
                o.w = 1.f / (1.f + expf(-(di.w * (u.w + di.w * sv.w) + c)));
                if (n0 + 3 < N_NODES) {
                    *(float4*)(out + n0) = o;
                } else {
                    if (n0 + 0 < N_NODES) out[n0 + 0] = o.x;
                    if (n0 + 1 < N_NODES) out[n0 + 1] = o.y;
                    if (n0 + 2 < N_NODES) out[n0 + 2] = o.z;
                    if (n0 + 3 < N_NODES) out[n0 + 3] = o.w;
                }
            }
        }
    }
}

// ------------------------- fallback (R1, validated) -------------------------
__global__ void wv_kernel(const float* __restrict__ W, const float* __restrict__ b,
                          const float* __restrict__ w2, const float* __restrict__ b2,
                          float* __restrict__ v, float* __restrict__ c) {
    int i = threadIdx.x;
    float acc = 0.f;
    for (int j = 0; j < HIDDEN; ++j) acc += W[i * HIDDEN + j] * w2[j];
    v[i] = acc;
    if (i == 0) {
        float cc = b2[0];
        for (int j = 0; j < HIDDEN; ++j) cc += b[j] * w2[j];
        *c = cc;
    }
}
__global__ void s_kernel(const float* __restrict__ x, const float* __restrict__ v,
                         float* __restrict__ s) {
    const int wave = threadIdx.x >> 6;
    const int lane = threadIdx.x & 63;
    const int n = blockIdx.x * 4 + wave;
    const float4* xr = (const float4*)(x + (size_t)n * IN_DIM);
    const float4* vr = (const float4*)v;
    float4 a  = xr[lane];
    float4 vv = vr[lane];
    float d = a.x * vv.x + a.y * vv.y + a.z * vv.z + a.w * vv.w;
    #pragma unroll
    for (int off = 32; off > 0; off >>= 1) d += __shfl_down(d, off, 64);
    if (lane == 0) s[n] = d;
}
__global__ void deg_kernel(const int* __restrict__ dst, int* __restrict__ cnt) {
    int e = blockIdx.x * blockDim.x + threadIdx.x;
    if (e < N_EDGES) atomicAdd(&cnt[dst[e]], 1);
}
__global__ void dinv_kernel(const int* __restrict__ cnt, const float* __restrict__ s,
                            float* __restrict__ dinv, float* __restrict__ t) {
    int n = blockIdx.x * blockDim.x + threadIdx.x;
    if (n < N_NODES) {
        float di = rsqrtf((float)(cnt[n] + 1));
        dinv[n] = di;
        t[n] = di * s[n];
    }
}
__global__ void scatter_kernel(const int* __restrict__ src, const int* __restrict__ dst,
                               const float* __restrict__ t, float* __restrict__ u) {
    int e = blockIdx.x * blockDim.x + threadIdx.x;
    if (e < N_EDGES) atomicAdd(&u[dst[e]], t[src[e]]);
}
__global__ void final_kernel(const float* __restrict__ dinv, const float* __restrict__ u,
                             const float* __restrict__ s, const float* __restrict__ c,
                             float* __restrict__ out) {
    int n = blockIdx.x * blockDim.x + threadIdx.x;
    if (n < N_NODES) {
        float di = dinv[n];
        float pre = di * (u[n] + di * s[n]) + c[0];
        out[n] = 1.f / (1.f + expf(-pre));
    }
}
// ----------------------------------------------------------------------------

extern "C" void kernel_launch(void* const* d_in, const int* in_sizes, int n_in,
                              void* d_out, int out_size, void* d_ws, size_t ws_size,
                              hipStream_t stream) {
    const float* x   = (const float*)d_in[0];   // [N, 256]
    const int*   ei  = (const int*)  d_in[1];   // [2, E]: src then dst
    const float* W   = (const float*)d_in[2];   // [256, 64]
    const float* b   = (const float*)d_in[3];   // [64]
    const float* w2  = (const float*)d_in[4];   // [64]
    const float* b2  = (const float*)d_in[5];   // [1]
    float* out = (float*)d_out;

    const int* src = ei;
    const int* dst = ei + N_EDGES;

    float* ws = (float*)d_ws;
    // word offsets
    int*      bar      = (int*)ws;                   // 2 ints (pad 128 words)
    float*    s        = ws + 128;                   // 100352
    float*    t        = ws + 100480;                // 100352
    float*    dinv     = ws + 200832;                // 100352
    unsigned* partialD = (unsigned*)(ws + 301184);   // 128*6400  =   819200
    float*    partialU = ws + 1120384;               // 512*12544 = 6,422,528
    const size_t need_bytes = (size_t)7542912 * 4;   // ~30.2 MB

    if (ws_size >= need_bytes) {
        hipMemsetAsync(d_ws, 0, 8, stream);          // zero barrier cnt+flag
        void* args[] = {(void*)&x, (void*)&W, (void*)&w2, (void*)&b, (void*)&b2,
                        (void*)&src, (void*)&dst, (void*)&partialD, (void*)&partialU,
                        (void*)&s, (void*)&t, (void*)&dinv, (void*)&bar, (void*)&out};
        (void)args;
        mono_kernel<<<NB, 1024, 0, stream>>>(x, W, w2, b, b2,
                                             (const int4*)src, (const int4*)dst,
                                             partialD, partialU, s, t, dinv, bar, out);
    } else {
        // fallback: validated device-atomic path
        float* v   = ws + 0;
        float* c   = ws + 256;
        float* sf  = ws + 512;
        float* tf  = ws + 100608;
        float* df  = ws + 200704;
        float* uu  = ws + 300800;
        int*   cn  = (int*)(ws + 400800);
        hipMemsetAsync((char*)d_ws + (size_t)300800 * 4, 0, (size_t)200000 * 4, stream);
        wv_kernel<<<1, 256, 0, stream>>>(W, b, w2, b2, v, c);
        s_kernel<<<N_NODES / 4, 256, 0, stream>>>(x, v, sf);
        deg_kernel<<<(N_EDGES + 255) / 256, 256, 0, stream>>>(dst, cn);
        dinv_kernel<<<(N_NODES + 255) / 256, 256, 0, stream>>>(cn, sf, df, tf);
        scatter_kernel<<<(N_EDGES + 255) / 256, 256, 0, stream>>>(src, dst, tf, uu);
        final_kernel<<<(N_NODES + 255) / 256, 256, 0, stream>>>(df, uu, sf, c, out);
    }
}

// Round 5
// 202.308 us; speedup vs baseline: 2.1558x; 2.1558x over previous
//
#include <hip/hip_runtime.h>
#include <math.h>

#define N_NODES 100000
#define N_EDGES 1600000
#define IN_DIM  256
#define HIDDEN  64

// ---- geometry ---------------------------------------------------------------
#define NB      512
// deg: 128 blocks = 32 chunks x 4 ranges (byte-packed, LDS 25.6 KB)
#define DEGB    128
#define D_CH    32
#define D_QPB   12500      // int4 groups per chunk (50000 edges)
#define D_PR    4
#define D_DNR   25600
#define D_DW    6400
// s-stream work stealing: 64-row chunks
#define NCHUNK  1563       // ceil(100000/64)
// scatter: 512 blocks = 64 chunks x 8 ranges (LDS 50,176 B, 2 blocks/CU)
#define S_CH    64
#define S_QPB   6250       // int4 groups per chunk (25000 edges)
#define S_SR    8
#define S_RANGE 12544

// ---------------------------------------------------------------------------
// K_A: blocks [0,128) do byte-packed degree histograms, then ALL 512 blocks
// work-steal 64-row chunks of the s-stream (s[n] = x[n].v, v = W.w2) from a
// global counter. The x-stream (only true HBM stream, 102.4 MB) gets the
// full machine for most of its duration instead of a static 75%.
// ---------------------------------------------------------------------------
__global__ void __launch_bounds__(1024) fusedA5_kernel(const float* __restrict__ x,
                                                       const float* __restrict__ W,
                                                       const float* __restrict__ w2,
                                                       const int4* __restrict__ dst4,
                                                       unsigned* __restrict__ partialD,
                                                       float* __restrict__ s,
                                                       int* __restrict__ wcnt) {
    __shared__ __align__(16) unsigned hist[D_DW];   // 25.6 KB
    __shared__ __align__(16) float vsh[IN_DIM];     // 1 KB
    __shared__ int chunk_sh;
    const int bid = blockIdx.x, tid = threadIdx.x;

    // v = W.w2 (every block; trivial, L2-hot)
    if (tid < IN_DIM) {
        const float4* wr  = (const float4*)(W + tid * HIDDEN);
        const float4* w2r = (const float4*)w2;
        float acc = 0.f;
        #pragma unroll
        for (int j = 0; j < HIDDEN / 4; ++j) {
            float4 a = wr[j], q = w2r[j];
            acc += a.x * q.x + a.y * q.y + a.z * q.z + a.w * q.w;
        }
        vsh[tid] = acc;
    }

    if (bid < DEGB) {
        const int r  = bid & (D_PR - 1);
        const int bb = bid >> 2;
        const int nbase = r * D_DNR;
        for (int i = tid; i < D_DW; i += 1024) hist[i] = 0u;
        __syncthreads();
        const int q0 = bb * D_QPB;
        for (int k = tid; k < D_QPB; k += 1024) {
            int4 d4 = dst4[q0 + k];
            int d0 = d4.x - nbase, d1 = d4.y - nbase, d2 = d4.z - nbase, d3 = d4.w - nbase;
            if ((unsigned)d0 < (unsigned)D_DNR) atomicAdd(&hist[d0 >> 2], 1u << ((d0 & 3) * 8));
            if ((unsigned)d1 < (unsigned)D_DNR) atomicAdd(&hist[d1 >> 2], 1u << ((d1 & 3) * 8));
            if ((unsigned)d2 < (unsigned)D_DNR) atomicAdd(&hist[d2 >> 2], 1u << ((d2 & 3) * 8));
            if ((unsigned)d3 < (unsigned)D_DNR) atomicAdd(&hist[d3 >> 2], 1u << ((d3 & 3) * 8));
        }
        __syncthreads();
        unsigned* outp = partialD + (size_t)bid * D_DW;
        for (int i = tid; i < D_DW; i += 1024) outp[i] = hist[i];
    }
    __syncthreads();

    // ---- work-stolen s-stream: 4 rows/wave, 16-lane groups -----------------
    const int wid  = tid >> 6;           // wave id 0..15
    const int lane = tid & 63;
    const int g    = lane >> 4;          // row-in-quad 0..3
    const int l16  = lane & 15;
    const float4* vr = (const float4*)vsh;
    float4 vv0 = vr[l16];
    float4 vv1 = vr[l16 + 16];
    float4 vv2 = vr[l16 + 32];
    float4 vv3 = vr[l16 + 48];
    for (;;) {
        if (tid == 0) chunk_sh = atomicAdd(wcnt, 1);
        __syncthreads();                 // publish chunk_sh
        const int c = chunk_sh;
        __syncthreads();                 // all read before next overwrite
        if (c >= NCHUNK) break;
        const int n0 = c * 64 + wid * 4 + g;
        if (n0 < N_NODES) {
            const float4* xr = (const float4*)(x + (size_t)n0 * IN_DIM);
            float4 a0 = xr[l16];
            float4 a1 = xr[l16 + 16];
            float4 a2 = xr[l16 + 32];
            float4 a3 = xr[l16 + 48];
            float d = a0.x * vv0.x + a0.y * vv0.y + a0.z * vv0.z + a0.w * vv0.w
                    + a1.x * vv1.x + a1.y * vv1.y + a1.z * vv1.z + a1.w * vv1.w
                    + a2.x * vv2.x + a2.y * vv2.y + a2.z * vv2.z + a2.w * vv2.w
                    + a3.x * vv3.x + a3.y * vv3.y + a3.z * vv3.z + a3.w * vv3.w;
            d += __shfl_down(d, 8, 16);
            d += __shfl_down(d, 4, 16);
            d += __shfl_down(d, 2, 16);
            d += __shfl_down(d, 1, 16);
            if (l16 == 0) s[n0] = d;
        }
    }
}

// ---------------------------------------------------------------------------
// K_B: merge byte-packed degree partials; dinv = rsqrt(deg+1), t = dinv*s.
// ---------------------------------------------------------------------------
__global__ void deg_merge_kernel(const unsigned* __restrict__ partialD,
                                 const float* __restrict__ s,
                                 float* __restrict__ dinv, float* __restrict__ t) {
    int w = blockIdx.x * blockDim.x + threadIdx.x;
    if (w >= N_NODES / 4) return;              // 25000 words cover all nodes
    const int r = w / D_DW, j = w - r * D_DW;
    unsigned a0 = 0, a1 = 0, a2 = 0, a3 = 0;
    #pragma unroll 8
    for (int bb = 0; bb < D_CH; ++bb) {
        unsigned p = partialD[(size_t)(bb * D_PR + r) * D_DW + j];
        a0 += p & 255u; a1 += (p >> 8) & 255u; a2 += (p >> 16) & 255u; a3 += p >> 24;
    }
    const int n0 = w * 4;                      // == r*D_DNR + j*4
    float4 sv = *(const float4*)(s + n0);
    float4 di, tv;
    di.x = rsqrtf((float)(a0 + 1)); di.y = rsqrtf((float)(a1 + 1));
    di.z = rsqrtf((float)(a2 + 1)); di.w = rsqrtf((float)(a3 + 1));
    tv.x = di.x * sv.x; tv.y = di.y * sv.y; tv.z = di.z * sv.z; tv.w = di.w * sv.w;
    *(float4*)(dinv + n0) = di;
    *(float4*)(t + n0) = tv;
}

// ---------------------------------------------------------------------------
// K_C: scatter u[dst] += t[src] via LDS-private accumulators.
// 512 blocks x 1024 threads (64 chunks x 8 ranges), 2 blocks/CU.
// ---------------------------------------------------------------------------
__global__ void __launch_bounds__(1024) scat_hist_kernel(const int4* __restrict__ src4,
                                                         const int4* __restrict__ dst4,
                                                         const float* __restrict__ t,
                                                         float* __restrict__ partialU) {
    __shared__ float acc[S_RANGE];
    const int r  = blockIdx.x & (S_SR - 1);
    const int bb = blockIdx.x >> 3;
    const int nbase = r * S_RANGE;
    for (int i = threadIdx.x; i < S_RANGE; i += 1024) acc[i] = 0.f;
    __syncthreads();
    const int q0 = bb * S_QPB;
    for (int k = threadIdx.x; k < S_QPB; k += 1024) {
        int4 d4 = dst4[q0 + k];
        int4 s4 = src4[q0 + k];
        int d0 = d4.x - nbase, d1 = d4.y - nbase, d2 = d4.z - nbase, d3 = d4.w - nbase;
        if ((unsigned)d0 < (unsigned)S_RANGE) atomicAdd(&acc[d0], t[s4.x]);
        if ((unsigned)d1 < (unsigned)S_RANGE) atomicAdd(&acc[d1], t[s4.y]);
        if ((unsigned)d2 < (unsigned)S_RANGE) atomicAdd(&acc[d2], t[s4.z]);
        if ((unsigned)d3 < (unsigned)S_RANGE) atomicAdd(&acc[d3], t[s4.w]);
    }
    __syncthreads();
    float* outp = partialU + (size_t)blockIdx.x * S_RANGE;
    for (int i = threadIdx.x; i < S_RANGE; i += 1024) outp[i] = acc[i];
}

// ---------------------------------------------------------------------------
// K_D: merge 64 scatter partials + sigmoid. 8 lanes per node-word (validated
// in R4 mono phase 4): 784 blocks x 256 -> latency spread across the machine.
// ---------------------------------------------------------------------------
__global__ void merge_final_kernel(const float* __restrict__ partialU,
                                   const float* __restrict__ dinv,
                                   const float* __restrict__ s,
                                   const float* __restrict__ b,
                                   const float* __restrict__ w2,
                                   const float* __restrict__ b2,
                                   float* __restrict__ out) {
    float c = b2[0];
    #pragma unroll 8
    for (int j = 0; j < HIDDEN; ++j) c += b[j] * w2[j];
    const int gid = blockIdx.x * blockDim.x + threadIdx.x;
    const int w = gid >> 3, p = gid & 7;     // 8 lanes per node-word
    if (w >= 25088) return;
    const int n0 = w * 4;
    const int r = n0 / S_RANGE, j = n0 - r * S_RANGE;
    float4 u = make_float4(0.f, 0.f, 0.f, 0.f);
    #pragma unroll
    for (int q = 0; q < 8; ++q) {
        float4 pp = *(const float4*)(partialU
                      + (size_t)((p + 8 * q) * S_SR + r) * S_RANGE + j);
        u.x += pp.x; u.y += pp.y; u.z += pp.z; u.w += pp.w;
    }
    #pragma unroll
    for (int off = 4; off > 0; off >>= 1) {
        u.x += __shfl_down(u.x, off, 8);
        u.y += __shfl_down(u.y, off, 8);
        u.z += __shfl_down(u.z, off, 8);
        u.w += __shfl_down(u.w, off, 8);
    }
    if (p == 0) {
        float4 di = *(const float4*)(dinv + n0);
        float4 sv = *(const float4*)(s + n0);
        float4 o;
        o.x = 1.f / (1.f + expf(-(di.x * (u.x + di.x * sv.x) + c)));
        o.y = 1.f / (1.f + expf(-(di.y * (u.y + di.y * sv.y) + c)));
        o.z = 1.f / (1.f + expf(-(di.z * (u.z + di.z * sv.z) + c)));
        o.w = 1.f / (1.f + expf(-(di.w * (u.w + di.w * sv.w) + c)));
        if (n0 + 3 < N_NODES) {
            *(float4*)(out + n0) = o;
        } else {
            if (n0 + 0 < N_NODES) out[n0 + 0] = o.x;
            if (n0 + 1 < N_NODES) out[n0 + 1] = o.y;
            if (n0 + 2 < N_NODES) out[n0 + 2] = o.z;
            if (n0 + 3 < N_NODES) out[n0 + 3] = o.w;
        }
    }
}

// ------------------------- fallback (R1, validated) -------------------------
__global__ void wv_kernel(const float* __restrict__ W, const float* __restrict__ b,
                          const float* __restrict__ w2, const float* __restrict__ b2,
                          float* __restrict__ v, float* __restrict__ c) {
    int i = threadIdx.x;
    float acc = 0.f;
    for (int j = 0; j < HIDDEN; ++j) acc += W[i * HIDDEN + j] * w2[j];
    v[i] = acc;
    if (i == 0) {
        float cc = b2[0];
        for (int j = 0; j < HIDDEN; ++j) cc += b[j] * w2[j];
        *c = cc;
    }
}
__global__ void s_kernel(const float* __restrict__ x, const float* __restrict__ v,
                         float* __restrict__ s) {
    const int wave = threadIdx.x >> 6;
    const int lane = threadIdx.x & 63;
    const int n = blockIdx.x * 4 + wave;
    const float4* xr = (const float4*)(x + (size_t)n * IN_DIM);
    const float4* vr = (const float4*)v;
    float4 a  = xr[lane];
    float4 vv = vr[lane];
    float d = a.x * vv.x + a.y * vv.y + a.z * vv.z + a.w * vv.w;
    #pragma unroll
    for (int off = 32; off > 0; off >>= 1) d += __shfl_down(d, off, 64);
    if (lane == 0) s[n] = d;
}
__global__ void deg_kernel(const int* __restrict__ dst, int* __restrict__ cnt) {
    int e = blockIdx.x * blockDim.x + threadIdx.x;
    if (e < N_EDGES) atomicAdd(&cnt[dst[e]], 1);
}
__global__ void dinv_kernel(const int* __restrict__ cnt, const float* __restrict__ s,
                            float* __restrict__ dinv, float* __restrict__ t) {
    int n = blockIdx.x * blockDim.x + threadIdx.x;
    if (n < N_NODES) {
        float di = rsqrtf((float)(cnt[n] + 1));
        dinv[n] = di;
        t[n] = di * s[n];
    }
}
__global__ void scatter_kernel(const int* __restrict__ src, const int* __restrict__ dst,
                               const float* __restrict__ t, float* __restrict__ u) {
    int e = blockIdx.x * blockDim.x + threadIdx.x;
    if (e < N_EDGES) atomicAdd(&u[dst[e]], t[src[e]]);
}
__global__ void final_kernel(const float* __restrict__ dinv, const float* __restrict__ u,
                             const float* __restrict__ s, const float* __restrict__ c,
                             float* __restrict__ out) {
    int n = blockIdx.x * blockDim.x + threadIdx.x;
    if (n < N_NODES) {
        float di = dinv[n];
        float pre = di * (u[n] + di * s[n]) + c[0];
        out[n] = 1.f / (1.f + expf(-pre));
    }
}
// ----------------------------------------------------------------------------

extern "C" void kernel_launch(void* const* d_in, const int* in_sizes, int n_in,
                              void* d_out, int out_size, void* d_ws, size_t ws_size,
                              hipStream_t stream) {
    const float* x   = (const float*)d_in[0];   // [N, 256]
    const int*   ei  = (const int*)  d_in[1];   // [2, E]: src then dst
    const float* W   = (const float*)d_in[2];   // [256, 64]
    const float* b   = (const float*)d_in[3];   // [64]
    const float* w2  = (const float*)d_in[4];   // [64]
    const float* b2  = (const float*)d_in[5];   // [1]
    float* out = (float*)d_out;

    const int* src = ei;
    const int* dst = ei + N_EDGES;

    float* ws = (float*)d_ws;
    // word offsets
    int*      wcnt     = (int*)ws;                   // 1 int (pad 128 words)
    float*    s        = ws + 128;                   // 100352
    float*    t        = ws + 100480;                // 100352
    float*    dinv     = ws + 200832;                // 100352
    unsigned* partialD = (unsigned*)(ws + 301184);   // 128*6400  =   819200
    float*    partialU = ws + 1120384;               // 512*12544 = 6,422,528
    const size_t need_bytes = (size_t)7542912 * 4;   // ~30.2 MB

    if (ws_size >= need_bytes) {
        hipMemsetAsync(d_ws, 0, 4, stream);          // zero work counter
        fusedA5_kernel<<<NB, 1024, 0, stream>>>(x, W, w2, (const int4*)dst,
                                                partialD, s, wcnt);
        deg_merge_kernel<<<(N_NODES / 4 + 255) / 256, 256, 0, stream>>>(partialD, s, dinv, t);
        scat_hist_kernel<<<S_CH * S_SR, 1024, 0, stream>>>((const int4*)src,
                                                           (const int4*)dst, t, partialU);
        merge_final_kernel<<<784, 256, 0, stream>>>(partialU, dinv, s, b, w2, b2, out);
    } else {
        // fallback: validated device-atomic path
        float* v   = ws + 0;
        float* c   = ws + 256;
        float* sf  = ws + 512;
        float* tf  = ws + 100608;
        float* df  = ws + 200704;
        float* uu  = ws + 300800;
        int*   cn  = (int*)(ws + 400800);
        hipMemsetAsync((char*)d_ws + (size_t)300800 * 4, 0, (size_t)200000 * 4, stream);
        wv_kernel<<<1, 256, 0, stream>>>(W, b, w2, b2, v, c);
        s_kernel<<<N_NODES / 4, 256, 0, stream>>>(x, v, sf);
        deg_kernel<<<(N_EDGES + 255) / 256, 256, 0, stream>>>(dst, cn);
        dinv_kernel<<<(N_NODES + 255) / 256, 256, 0, stream>>>(cn, sf, df, tf);
        scatter_kernel<<<(N_EDGES + 255) / 256, 256, 0, stream>>>(src, dst, tf, uu);
        final_kernel<<<(N_NODES + 255) / 256, 256, 0, stream>>>(df, uu, sf, c, out);
    }
}